// Round 1
// baseline (96.770 us; speedup 1.0000x reference)
//
#include <hip/hip_runtime.h>
#include <hip/hip_bf16.h>

typedef unsigned short u16;
typedef __attribute__((ext_vector_type(8))) short short8;
typedef __attribute__((ext_vector_type(4))) float floatx4;

#define NROWS 8192
#define DIM 256

__device__ __forceinline__ void atomicMinFloat(float* addr, float val) {
    if (val >= 0.0f) {
        atomicMin((int*)addr, __float_as_int(val));
    } else {
        atomicMax((unsigned int*)addr, __float_as_uint(val));
    }
}

__device__ __forceinline__ u16 f32_to_bf16_rne(float x) {
    unsigned int u = __float_as_uint(x);
    unsigned int r = (u + 0x7fffu + ((u >> 16) & 1u)) >> 16;
    return (u16)r;
}

// C(M) = -logp * exp(logp); quasiconcave in M => rowmin = min(C(minM), C(maxM)).
__device__ __forceinline__ float c_of_m(float m) {
    const float INV_SIG = 1.0f / 0.3f;
    const float KC = 0.28503427f;  // -ln(0.3) - 0.5*ln(2*pi)
    float z = (m - 1.0f) * INV_SIG;
    float logp = fmaf(-0.5f * z, z, KC);
    return -logp * __expf(logp);
}

// 16B async DMA global -> LDS. LDS dest is wave-uniform base + lane*16.
__device__ __forceinline__ void load16(const u16* g, u16* l) {
    __builtin_amdgcn_global_load_lds(
        (__attribute__((address_space(1))) void*)g,
        (__attribute__((address_space(3))) void*)l, 16, 0, 0);
}

// Normalize rows (L2-norm clamped at 1e-8), wave per row, float4 loads.
// BOTH X and Y are written in MFMA fragment ("panel") layout:
//   element (row r, k) -> flat[ ((p*8+kt)*64 + lq*16 + lm)*8 + j ]
//   p=r>>4, lm=r&15, kt=k>>5, lq=(k>>3)&3, j=k&7.
// A fragment load is then base + lane*16B: one coalesced dwordx4.
// Verified end-to-end R5/R11/R14/R15 (absmax 1.5e-5).
__global__ __launch_bounds__(256) void normalize_kernel(const float* __restrict__ Ex,
                                                        const float* __restrict__ Ey,
                                                        u16* __restrict__ Xs,
                                                        u16* __restrict__ Ys,
                                                        float* __restrict__ out) {
    const int t = threadIdx.x;
    const int ln = t & 63;
    const int row = blockIdx.x * 4 + (t >> 6);
    const float* src = (blockIdx.y == 0) ? Ex : Ey;
    u16* dst = (blockIdx.y == 0) ? Xs : Ys;

    float4 v = *(const float4*)(src + (size_t)row * DIM + ln * 4);
    float s = fmaf(v.x, v.x, fmaf(v.y, v.y, fmaf(v.z, v.z, v.w * v.w)));
    #pragma unroll
    for (int m = 32; m >= 1; m >>= 1) s += __shfl_xor(s, m, 64);
    float inv = 1.0f / fmaxf(sqrtf(s), 1e-8f);

    ushort4 o;
    o.x = f32_to_bf16_rne(v.x * inv);
    o.y = f32_to_bf16_rne(v.y * inv);
    o.z = f32_to_bf16_rne(v.z * inv);
    o.w = f32_to_bf16_rne(v.w * inv);

    const int p = row >> 4;
    const int lm = row & 15;
    const int kt = ln >> 3;
    const int lq = (ln >> 1) & 3;
    const int j4 = (ln & 1) * 4;
    const size_t off = ((size_t)((p * 8 + kt) * 64 + lq * 16 + lm)) * 8 + j4;
    *(ushort4*)(dst + off) = o;

    if (blockIdx.y == 0 && ln == 0) out[row] = __uint_as_float(0x7f800000u);  // +inf
}

// Block = 512 rows x 512 cols, 512 threads = 8 waves, each wave a distinct
// 64-row group (zero A duplication); all waves share each 64-col B tile.
// R16 structure: B0 DMA first (hides under A k0/k1 loads), A kt=2..7 issue
// after the barrier pipelined against ct=0's MFMA stream; cts 1..7 are the
// steady double-buffered loop. Staged traffic 0.5 MB/CU.
// R17 changes:
//  (1) zeroAcc eliminated -- every ct's kt=0 MFMA takes a zero C operand, so
//      the 64 v_mov per wave per ct (post-barrier serial VALU) are gone.
//  (2) T5 s_setprio(1) around each 16-MFMA cluster (prio 0 for ds_read /
//      stage / fold) -- with 2 waves/SIMD the scheduler now prefers the wave
//      that is feeding the matrix pipe.
// Grid 256 (1 block/CU): b&15 = row-tile, b>>4 = col-group.
__global__ void __launch_bounds__(512, 2)
gemm_min_kernel(const u16* __restrict__ Xs,
                const u16* __restrict__ Ys,
                float* __restrict__ out) {
    __shared__ u16 Bs[2][32 * 512];  // 2 x 32 KB

    const int tid = threadIdx.x;
    const int w = tid >> 6;      // 0..7 row-group
    const int lane = tid & 63;
    const int lq = lane >> 4;
    const int lm = lane & 15;

    const int b = blockIdx.x;
    const int rowStart = (b & 15) * 512;
    const int rowPan0 = (b & 15) * 32 + w * 4;
    const u16* ybase = Ys + (size_t)((b >> 4) * 32) * 4096;  // advances 16384/ct

    // Stage one 64col x 256k B tile (32 KB = 32 x 1 KB units) via DMA.
    // 8 waves x 4 units; unit u -> (panel u>>3, kt u&7); LDS slot u*512 so
    // fragment reads are Bs[(cg*8+kt)*512 + lane*8] (b128, conflict-free).
    auto stageB = [&](int buf, const u16* yb) {
        #pragma unroll
        for (int i = 0; i < 4; ++i) {
            const int u = w * 4 + i;
            load16(yb + (u >> 3) * 4096 + (u & 7) * 512 + lane * 8,
                   &Bs[buf][u * 512]);
        }
    };

    short8 a[4][8];
    auto loadA = [&](int kt) {
        #pragma unroll
        for (int rg = 0; rg < 4; ++rg)
            a[rg][kt] = *(const short8*)(
                Xs + ((size_t)(rowPan0 + rg) * 8 + kt) * 512 + lane * 8);
    };

    floatx4 mn4[4], mx4[4];
    #pragma unroll
    for (int rg = 0; rg < 4; ++rg) {
        mn4[rg] = (floatx4){3.4e38f, 3.4e38f, 3.4e38f, 3.4e38f};
        mx4[rg] = (floatx4){-3.4e38f, -3.4e38f, -3.4e38f, -3.4e38f};
    }

    floatx4 acc[4][4];
    const floatx4 FZ = (floatx4){0.0f, 0.0f, 0.0f, 0.0f};

    // kt=0 writes acc with a zero C operand (no zeroAcc pass); kt>=1
    // accumulates. setprio(1) wraps only the MFMA clusters.
    auto compute = [&](int buf) {
        #pragma unroll
        for (int kt = 0; kt < 8; ++kt) {
            short8 bf[4];
            #pragma unroll
            for (int cg = 0; cg < 4; ++cg)
                bf[cg] = *(const short8*)(&Bs[buf][(cg * 8 + kt) * 512 + lane * 8]);
            __builtin_amdgcn_s_setprio(1);
            if (kt == 0) {
                #pragma unroll
                for (int cg = 0; cg < 4; ++cg)
                    #pragma unroll
                    for (int rg = 0; rg < 4; ++rg)
                        acc[rg][cg] = __builtin_amdgcn_mfma_f32_16x16x32_bf16(
                            a[rg][0], bf[cg], FZ, 0, 0, 0);
            } else {
                #pragma unroll
                for (int cg = 0; cg < 4; ++cg)
                    #pragma unroll
                    for (int rg = 0; rg < 4; ++rg)
                        acc[rg][cg] = __builtin_amdgcn_mfma_f32_16x16x32_bf16(
                            a[rg][kt], bf[cg], acc[rg][cg], 0, 0, 0);
            }
            __builtin_amdgcn_s_setprio(0);
        }
    };
    auto fold = [&]() {
        #pragma unroll
        for (int rg = 0; rg < 4; ++rg)
            #pragma unroll
            for (int cg = 0; cg < 4; ++cg)
                #pragma unroll
                for (int r = 0; r < 4; ++r) {
                    float m = acc[rg][cg][r];
                    mn4[rg][r] = fminf(mn4[rg][r], m);
                    mx4[rg][r] = fmaxf(mx4[rg][r], m);
                }
    };

    // --- ct = 0, peeled: overlap A prologue with B0 DMA + early compute ---
    stageB(0, ybase);        // B0 DMA first (hides under the A k0/k1 loads)
    loadA(0);
    loadA(1);
    __syncthreads();         // drains B0 DMA (+ the 8 early A loads)
    stageB(1, ybase + 16384);  // prefetch ct=1
    // Remaining A loads: issued ahead of ct=0's MFMA stream; vmcnt pipelining
    // drains them behind the first k-steps (exposure ~1 k-step, not ~25k cyc).
    loadA(2); loadA(3); loadA(4); loadA(5); loadA(6); loadA(7);
    compute(0);
    fold();
    ybase += 16384;

    // --- cts 1..7: steady state ---
    #pragma unroll 1
    for (int ct = 1; ct < 8; ++ct) {
        const int buf = ct & 1;
        __syncthreads();           // drains ct's B DMA
        if (ct < 7)
            stageB(buf ^ 1, ybase + 16384);  // prefetch ct+1
        compute(buf);
        fold();
        ybase += 16384;  // loop-carried: blocks cross-ct hoisting
    }

    // Single epilogue: quad-lane reduce, eval C twice (quasiconcavity),
    // fire-and-forget atomicMin (no read guard -- R3 post-mortem).
    #pragma unroll
    for (int rg = 0; rg < 4; ++rg) {
        #pragma unroll
        for (int r = 0; r < 4; ++r) {
            float mn = mn4[rg][r];
            float mx = mx4[rg][r];
            #pragma unroll
            for (int mofs = 1; mofs < 16; mofs <<= 1) {
                mn = fminf(mn, __shfl_xor(mn, mofs, 64));
                mx = fmaxf(mx, __shfl_xor(mx, mofs, 64));
            }
            if (lm == 0) {
                float cmin = fminf(c_of_m(mn), c_of_m(mx));
                int row = rowStart + w * 64 + rg * 16 + lq * 4 + r;
                atomicMinFloat(&out[row], cmin);
            }
        }
    }
}

extern "C" void kernel_launch(void* const* d_in, const int* in_sizes, int n_in,
                              void* d_out, int out_size, void* d_ws, size_t ws_size,
                              hipStream_t stream) {
    const float* Ex = (const float*)d_in[0];
    const float* Ey = (const float*)d_in[1];
    float* out = (float*)d_out;
    u16* Xs = (u16*)d_ws;                // 4 MB, panel layout
    u16* Ys = Xs + (size_t)NROWS * DIM;  // 4 MB, panel layout

    hipLaunchKernelGGL(normalize_kernel, dim3(NROWS / 4, 2), dim3(256), 0, stream,
                       Ex, Ey, Xs, Ys, out);
    hipLaunchKernelGGL(gemm_min_kernel, dim3(16 * 16), dim3(512), 0, stream,
                       Xs, Ys, out);
}